// Round 6
// baseline (847.018 us; speedup 1.0000x reference)
//
#include <hip/hip_runtime.h>
#include <stdint.h>

#define NN 50000
#define NE 800000
#define CH 128

typedef double d4 __attribute__((ext_vector_type(4)));

// ---------------- threefry2x32 (exact JAX semantics) ----------------
__host__ __device__ inline void tf2x32(uint32_t k0, uint32_t k1, uint32_t& x0, uint32_t& x1) {
  uint32_t ks2 = k0 ^ k1 ^ 0x1BD11BDAu;
  x0 += k0; x1 += k1;
#define ROTL(v, r) (((v) << (r)) | ((v) >> (32 - (r))))
#define RND(r) { x0 += x1; x1 = ROTL(x1, r); x1 ^= x0; }
  RND(13) RND(15) RND(26) RND(6)
  x0 += k1; x1 += ks2 + 1u;
  RND(17) RND(29) RND(16) RND(24)
  x0 += ks2; x1 += k0 + 2u;
  RND(13) RND(15) RND(26) RND(6)
  x0 += k0; x1 += k1 + 3u;
  RND(17) RND(29) RND(16) RND(24)
  x0 += k1; x1 += ks2 + 4u;
  RND(13) RND(15) RND(26) RND(6)
  x0 += ks2; x1 += k0 + 5u;
#undef RND
#undef ROTL
}

__device__ inline float bits_to_u(uint32_t b) {
  float f = __uint_as_float(0x3F800000u | (b >> 9)) - 1.0f;  // [0,1)
  f = f + 1e-10f;
  return fmaxf(1e-10f, f);
}

// ---------------- graph preprocessing ----------------
__global__ __launch_bounds__(256) void deg_k(const int* __restrict__ dst, int* __restrict__ degi) {
  int i = blockIdx.x * 256 + threadIdx.x;
  if (i < NE) atomicAdd(&degi[dst[i]], 1);
}

__global__ __launch_bounds__(256) void dinv_k(const int* __restrict__ degi, float* __restrict__ dinv) {
  int n = blockIdx.x * 256 + threadIdx.x;
  if (n < NN) {
    float d = (float)(degi[n] + 1);
    dinv[n] = 1.0f / sqrtf(d);
  }
}

__global__ __launch_bounds__(256) void scan1_k(const int* __restrict__ degi, int* __restrict__ offs,
                                               int* __restrict__ part) {
  __shared__ int tmp[256];
  int t = threadIdx.x, b = blockIdx.x, i = b * 256 + t;
  int v = (i < NN) ? degi[i] : 0;
  tmp[t] = v;
  __syncthreads();
  for (int s = 1; s < 256; s <<= 1) {
    int a = (t >= s) ? tmp[t - s] : 0;
    __syncthreads();
    tmp[t] += a;
    __syncthreads();
  }
  int incl = tmp[t];
  if (i < NN) offs[i] = incl - v;
  if (t == 255) part[b] = incl;
}

__global__ void scan2_k(int* part, int nparts) {
  if (threadIdx.x == 0 && blockIdx.x == 0) {
    int run = 0;
    for (int i = 0; i < nparts; ++i) { int v = part[i]; part[i] = run; run += v; }
  }
}

__global__ __launch_bounds__(256) void scan3_k(int* __restrict__ offs, const int* __restrict__ part) {
  int i = blockIdx.x * 256 + threadIdx.x;
  if (i < NN) offs[i] += part[blockIdx.x];
  if (i == 0) offs[NN] = NE;
}

__global__ __launch_bounds__(256) void place_k(const int* __restrict__ dst, const int* __restrict__ offs,
                                               int* __restrict__ cnt, int* __restrict__ eids) {
  int i = blockIdx.x * 256 + threadIdx.x;
  if (i < NE) {
    int d = dst[i];
    int p = offs[d] + atomicAdd(&cnt[d], 1);
    eids[p] = i;
  }
}

// deterministic intra-bucket order = ascending edge id (matches ref segment-sum order)
__global__ __launch_bounds__(256) void sort_k(const int* __restrict__ offs, int* __restrict__ eids) {
  int n = blockIdx.x * 256 + threadIdx.x;
  if (n >= NN) return;
  int s0 = offs[n], s1 = offs[n + 1];
  for (int i = s0 + 1; i < s1; ++i) {
    int v = eids[i];
    int j = i - 1;
    while (j >= s0 && eids[j] > v) { eids[j + 1] = eids[j]; --j; }
    eids[j + 1] = v;
  }
}

// gather src + norm per sorted edge slot; srcs may alias eids (in-place, own-slot RMW)
__global__ __launch_bounds__(256) void gath_k(const int* __restrict__ eids, const int* __restrict__ src,
                                              const int* __restrict__ dst, const float* __restrict__ dinv,
                                              int* __restrict__ srcs, float* __restrict__ norms) {
  int p = blockIdx.x * 256 + threadIdx.x;
  if (p < NE) {
    int e = eids[p];
    int s = src[e];
    float nm = dinv[s] * dinv[dst[e]];
    srcs[p] = s;
    norms[p] = nm;
  }
}

// ---------------- gumbel precompute ----------------
__global__ __launch_bounds__(256) void gum_k(float* __restrict__ gum,
                                             uint32_t k00, uint32_t k01, uint32_t k10, uint32_t k11,
                                             uint32_t k20, uint32_t k21) {
  int i = blockIdx.x * 256 + threadIdx.x;
  if (i >= 3 * NN) return;
  int l = i / NN;
  int n = i - l * NN;
  uint32_t kx, ky;
  if (l == 0) { kx = k00; ky = k01; }
  else if (l == 1) { kx = k10; ky = k11; }
  else { kx = k20; ky = k21; }
  int j0 = 2 * n, j1 = 2 * n + 1;
  uint32_t w0, w1;
  if (j0 < NN) {
    uint32_t a0 = (uint32_t)j0, a1 = (uint32_t)(j0 + NN);
    tf2x32(kx, ky, a0, a1); w0 = a0;
    uint32_t b0 = (uint32_t)j1, b1 = (uint32_t)(j1 + NN);
    tf2x32(kx, ky, b0, b1); w1 = b0;
  } else {
    uint32_t a0 = (uint32_t)(j0 - NN), a1 = (uint32_t)j0;
    tf2x32(kx, ky, a0, a1); w0 = a1;
    uint32_t b0 = (uint32_t)(j1 - NN), b1 = (uint32_t)j1;
    tf2x32(kx, ky, b0, b1); w1 = b1;
  }
  float u0 = bits_to_u(w0), u1 = bits_to_u(w1);
  gum[2 * (size_t)i]     = -logf(-logf(u0));
  gum[2 * (size_t)i + 1] = -logf(-logf(u1));
}

// init exit_layers to 3.0 (doubles as the "still active" state)
__global__ __launch_bounds__(256) void einit_k(float* __restrict__ eout) {
  int i = blockIdx.x * 256 + threadIdx.x;
  if (i < NN) eout[i] = 3.0f;
}

// ---------------- h = x @ W  (f32, 64x128 tile, BK=32, float4 both operands) ----------------
// k-order per output element is strictly ascending -> bit-identical to the verified lin.
// Writes h in channel-sliced layout hs[cb][n][16], cb = c/16.
__global__ __launch_bounds__(256) void lin_k(const float* __restrict__ x, const float* __restrict__ W,
                                             float* __restrict__ hs) {
  __shared__ float Ws[32 * 128];    // [k][c]
  __shared__ float xs[64][36];      // [row][k], padded
  int t = threadIdx.x;
  int row0 = blockIdx.x << 6;
  int tr = t & 15, tc = t >> 4;     // thread tile: rows tr+16i, col4s tc and tc+16
  float4 acc[4][2];
#pragma unroll
  for (int i = 0; i < 4; ++i) { acc[i][0] = make_float4(0,0,0,0); acc[i][1] = make_float4(0,0,0,0); }

  for (int kt = 0; kt < 4; ++kt) {
    __syncthreads();
    {
      const float4* W4 = (const float4*)(W + (size_t)(kt * 32) * 128);
      float4* Ws4 = (float4*)Ws;
#pragma unroll
      for (int i = 0; i < 4; ++i) Ws4[t + 256 * i] = W4[t + 256 * i];
    }
    {
#pragma unroll
      for (int i = 0; i < 2; ++i) {
        int f = t + 256 * i;            // 0..511
        int row = f >> 3, c4 = f & 7;
        int gr = row0 + row;
        float4 v = make_float4(0,0,0,0);
        if (gr < NN) v = ((const float4*)x)[(size_t)gr * 32 + kt * 8 + c4];
        *(float4*)&xs[row][4 * c4] = v;
      }
    }
    __syncthreads();
    const float4* Ws4 = (const float4*)Ws;
#pragma unroll
    for (int kk = 0; kk < 32; kk += 4) {
      float4 xv[4];
#pragma unroll
      for (int i = 0; i < 4; ++i) xv[i] = *(const float4*)&xs[tr + 16 * i][kk];
#pragma unroll
      for (int d = 0; d < 4; ++d) {
        float4 w0 = Ws4[(kk + d) * 32 + tc];
        float4 w1 = Ws4[(kk + d) * 32 + 16 + tc];
#pragma unroll
        for (int i = 0; i < 4; ++i) {
          float xd = ((const float*)&xv[i])[d];
          acc[i][0].x += xd * w0.x; acc[i][0].y += xd * w0.y;
          acc[i][0].z += xd * w0.z; acc[i][0].w += xd * w0.w;
          acc[i][1].x += xd * w1.x; acc[i][1].y += xd * w1.y;
          acc[i][1].z += xd * w1.z; acc[i][1].w += xd * w1.w;
        }
      }
    }
  }
  // store to sliced layout: colA = 4*tc (slice tc>>2), colB = 64+4*tc (slice 4+(tc>>2))
  int cbA = tc >> 2, off4 = tc & 3;  // float4 index within 16-ch slice
#pragma unroll
  for (int i = 0; i < 4; ++i) {
    int gr = row0 + tr + 16 * i;
    if (gr < NN) {
      ((float4*)hs)[((size_t)cbA * NN + gr) * 4 + off4] = acc[i][0];
      ((float4*)hs)[((size_t)(cbA + 4) * NN + gr) * 4 + off4] = acc[i][1];
    }
  }
}

// ---------------- sym-normalized aggregate + bias (+ GELU), channel-sliced ----------------
__device__ inline float gelu_exact(float v) {
  return 0.5f * v * (1.0f + erff(v / 1.4142135623730951f));
}

// Block: cb = blockIdx&7 (XCD-pinned slice), 4 waves x 4 nodes.
// Wave lanes: c = lane&15 (channel), e = lane>>4 (edge slot). Per-channel f64 sums,
// fixed order (e-strided ascending + tree reduce) -> deterministic.
__global__ __launch_bounds__(256) void agg_k(const float* __restrict__ hs, const float* __restrict__ dinv,
                                             const int* __restrict__ offs, const int* __restrict__ srcs,
                                             const float* __restrict__ norms, const float* __restrict__ bias,
                                             float* __restrict__ xout, int act) {
  int t = threadIdx.x;
  int lane = t & 63, w = t >> 6;
  int cb = blockIdx.x & 7;
  int grp = blockIdx.x >> 3;
  int c = lane & 15, e = lane >> 4;
  const float* hb = hs + (size_t)cb * NN * 16;
  float bv = bias[cb * 16 + c];

  for (int q = 0; q < 4; ++q) {
    int n = grp * 16 + w * 4 + q;
    int s0 = offs[n], s1 = offs[n + 1];
    double a = 0.0;
    // first 32 edges: all descriptor loads issued up-front (parallel), then h loads
    int sA[8]; float nA[8];
#pragma unroll
    for (int j = 0; j < 8; ++j) {
      int p = s0 + 4 * j + e;
      bool v = p < s1;
      sA[j] = v ? __builtin_nontemporal_load(&srcs[p]) : n;
      nA[j] = v ? __builtin_nontemporal_load(&norms[p]) : 0.0f;
    }
    float hv[8];
#pragma unroll
    for (int j = 0; j < 8; ++j) hv[j] = hb[(size_t)sA[j] * 16 + c];
#pragma unroll
    for (int j = 0; j < 8; ++j) a += (double)(hv[j] * nA[j]);
    // rare tail (deg > 32)
    for (int p0 = s0 + 32; p0 < s1; p0 += 4) {
      int p = p0 + e;
      int s = n; float nm = 0.0f;
      if (p < s1) { s = __builtin_nontemporal_load(&srcs[p]); nm = __builtin_nontemporal_load(&norms[p]); }
      float h2 = hb[(size_t)s * 16 + c];
      a += (double)(h2 * nm);
    }
    // reduce over e-slots: ((e0+e1)+(e2+e3)), fixed tree
    a += __shfl_xor(a, 16);
    a += __shfl_xor(a, 32);
    // self-loop appended last (like ref)
    float dv = dinv[n];
    float hn = hb[(size_t)n * 16 + c];
    a += (double)(hn * (dv * dv));
    float r = (float)a + bv;
    if (act) r = gelu_exact(r);
    if (e == 0) xout[(size_t)n * CH + cb * 16 + c] = r;
  }
}

// ---------------- confidence MLP + gumbel decision via f64 MFMA ----------------
// NO atomics, NO state array: eout (init 3.0) is the state. Numerics identical
// to the verified r4/r5 kernel.
template <int MODE>
__global__ __launch_bounds__(256) void decide_k(const float* __restrict__ x, const float* __restrict__ W1,
                                                const float* __restrict__ b1, const float* __restrict__ W2,
                                                const float* __restrict__ b2, const float* __restrict__ gum,
                                                float* __restrict__ zout, float* __restrict__ eout,
                                                float layerf) {
  __shared__ float W1s[128][68];   // padded, float4-aligned rows
  __shared__ float b1s[64];
  __shared__ float w2s[128];
  __shared__ float b2s[2];
  __shared__ float xs[4][16][132];
  int t = threadIdx.x;
#pragma unroll
  for (int i = 0; i < 8; ++i) {
    int e4 = t + 256 * i;
    float4 v = ((const float4*)W1)[e4];
    *(float4*)&W1s[e4 >> 4][4 * (e4 & 15)] = v;
  }
  if (t < 64) b1s[t] = b1[t];
  if (t < 128) w2s[t] = W2[t];
  if (t < 2) b2s[t] = b2[t];

  int lane = t & 63, w = t >> 6;
  int n0 = blockIdx.x * 64 + w * 16;
#pragma unroll
  for (int i = 0; i < 8; ++i) {
    int f = lane + 64 * i;
    int row = f >> 5, c4 = f & 31;
    int gr = n0 + row;
    float4 v = make_float4(0.f, 0.f, 0.f, 0.f);
    if (gr < NN) v = ((const float4*)x)[(size_t)gr * 32 + c4];
    *(float4*)&xs[w][row][4 * c4] = v;
  }
  __syncthreads();

  int g = lane >> 4, r = lane & 15;
  bool writer = (r < 4);
  int mynode = n0 + 4 * g + r;
  float ev = 3.0f;
  if (MODE > 0 && writer && mynode < NN) ev = eout[mynode];
  bool m_act = writer && (mynode < NN) && (MODE == 0 || ev == 3.0f);
  unsigned long long actmask = __ballot(m_act);
  if (MODE > 0 && actmask == 0ULL) return;

  d4 acc0 = {0., 0., 0., 0.}, acc1 = {0., 0., 0., 0.};
  d4 acc2 = {0., 0., 0., 0.}, acc3 = {0., 0., 0., 0.};
#pragma unroll 4
  for (int ks = 0; ks < 32; ++ks) {
    int k = 4 * ks + g;
    double av = (double)xs[w][r][k];
    double b0 = (double)W1s[k][r];
    double b1v = (double)W1s[k][16 + r];
    double b2v = (double)W1s[k][32 + r];
    double b3v = (double)W1s[k][48 + r];
    acc0 = __builtin_amdgcn_mfma_f64_16x16x4f64(av, b0, acc0, 0, 0, 0);
    acc1 = __builtin_amdgcn_mfma_f64_16x16x4f64(av, b1v, acc1, 0, 0, 0);
    acc2 = __builtin_amdgcn_mfma_f64_16x16x4f64(av, b2v, acc2, 0, 0, 0);
    acc3 = __builtin_amdgcn_mfma_f64_16x16x4f64(av, b3v, acc3, 0, 0, 0);
  }

  double p0[4], p1[4];
#pragma unroll
  for (int i = 0; i < 4; ++i) {
    float h0 = fmaxf((float)acc0[i] + b1s[r], 0.f);
    float h1 = fmaxf((float)acc1[i] + b1s[16 + r], 0.f);
    float h2 = fmaxf((float)acc2[i] + b1s[32 + r], 0.f);
    float h3 = fmaxf((float)acc3[i] + b1s[48 + r], 0.f);
    double q0 = (double)h0 * (double)w2s[2 * r] + (double)h1 * (double)w2s[2 * (16 + r)] +
                (double)h2 * (double)w2s[2 * (32 + r)] + (double)h3 * (double)w2s[2 * (48 + r)];
    double q1 = (double)h0 * (double)w2s[2 * r + 1] + (double)h1 * (double)w2s[2 * (16 + r) + 1] +
                (double)h2 * (double)w2s[2 * (32 + r) + 1] + (double)h3 * (double)w2s[2 * (48 + r) + 1];
#pragma unroll
    for (int off = 1; off <= 8; off <<= 1) {
      q0 += __shfl_xor(q0, off);
      q1 += __shfl_xor(q1, off);
    }
    p0[i] = q0; p1[i] = q1;
  }

  double q0sel = p0[0], q1sel = p1[0];
  if (r == 1) { q0sel = p0[1]; q1sel = p1[1]; }
  if (r == 2) { q0sel = p0[2]; q1sel = p1[2]; }
  if (r == 3) { q0sel = p0[3]; q1sel = p1[3]; }
  bool myex = false;
  if (writer && mynode < NN) {
    float gg0 = gum[2 * (size_t)mynode];
    float gg1 = gum[2 * (size_t)mynode + 1];
    float l0 = (float)q0sel + b2s[0];
    float l1 = (float)q1sel + b2s[1];
    myex = (l1 + gg1) > (l0 + gg0);
  }
  unsigned long long exmask = __ballot(myex);

  if (m_act && myex) eout[mynode] = layerf;

#pragma unroll
  for (int i = 0; i < 16; ++i) {
    int bitpos = 16 * (i >> 2) + (i & 3);
    bool a = (actmask >> bitpos) & 1ULL;
    bool ee = (exmask >> bitpos) & 1ULL;
    if (a && (MODE == 2 || ee)) {
      int node = n0 + i;
      float2 v;
      v.x = xs[w][i][2 * lane];
      v.y = xs[w][i][2 * lane + 1];
      *(float2*)&zout[(size_t)node * CH + 2 * lane] = v;
    }
  }
}

// single-block count of active[] from eout; no atomics
__global__ __launch_bounds__(1024) void cnt_k(const float* __restrict__ eout, float* __restrict__ aout) {
  __shared__ int s1[16], s2[16];
  int t = threadIdx.x;
  int c1 = 0, c2 = 0;
  for (int i = t; i < NN; i += 1024) {
    float v = eout[i];
    c1 += (v < 0.5f);
    c2 += (v < 1.5f);
  }
#pragma unroll
  for (int off = 32; off >= 1; off >>= 1) { c1 += __shfl_xor(c1, off); c2 += __shfl_xor(c2, off); }
  if ((t & 63) == 0) { s1[t >> 6] = c1; s2[t >> 6] = c2; }
  __syncthreads();
  if (t == 0) {
    int a1 = 0, a2 = 0;
#pragma unroll
    for (int i = 0; i < 16; ++i) { a1 += s1[i]; a2 += s2[i]; }
    aout[0] = 50000.0f;
    aout[1] = (float)(NN - a1);
    aout[2] = (float)(NN - a2);
  }
}

// ---------------- host ----------------
extern "C" void kernel_launch(void* const* d_in, const int* in_sizes, int n_in,
                              void* d_out, int out_size, void* d_ws, size_t ws_size,
                              hipStream_t stream) {
  const float* x_in = (const float*)d_in[0];
  const int* eidx = (const int*)d_in[1];
  const int* esrc = eidx;
  const int* edst = eidx + NE;
  const float* convw[3] = {(const float*)d_in[2], (const float*)d_in[4], (const float*)d_in[6]};
  const float* convb[3] = {(const float*)d_in[3], (const float*)d_in[5], (const float*)d_in[7]};
  const float* cw1 = (const float*)d_in[8];
  const float* cb1 = (const float*)d_in[9];
  const float* cw2 = (const float*)d_in[10];
  const float* cb2 = (const float*)d_in[11];
  // d_in[12] = temp_w: unused (temperature > 0 cancels in the argmax)

  float* out = (float*)d_out;
  float* zout = out;
  float* eout = out + (size_t)NN * CH;
  float* aout = eout + NN;

  char* w = (char*)d_ws;
  float* P = (float*)w;   w += (size_t)NN * CH * 4;   // hs (sliced)
  float* Q = (float*)w;   w += (size_t)NN * CH * 4;   // x (node-major)
  int* eids = (int*)w;    w += (size_t)NE * 4;        // becomes srcs in-place after gath_k
  float* norms = (float*)w; w += (size_t)NE * 4;
  float* gum = (float*)w; w += (size_t)3 * NN * 2 * 4;
  int* offs = (int*)w;    w += (size_t)(NN + 1) * 4;
  float* dinv = (float*)w; w += (size_t)NN * 4;
  char* zr0 = w;
  int* degi = (int*)w;    w += (size_t)NN * 4;
  int* cnt = (int*)w;     w += (size_t)NN * 4;
  int* parts = (int*)w;   w += 1024;

  hipMemsetAsync(zr0, 0, (size_t)(2 * NN) * 4, stream);

  uint32_t key[3][2];
  for (int l = 0; l < 3; ++l) {
    uint32_t a = 0u, b = (uint32_t)l;
    tf2x32(0u, 42u, a, b);
    key[l][0] = a; key[l][1] = b;
  }

  const int nblkN = (NN + 255) / 256;
  deg_k<<<(NE + 255) / 256, 256, 0, stream>>>(edst, degi);
  dinv_k<<<nblkN, 256, 0, stream>>>(degi, dinv);
  scan1_k<<<nblkN, 256, 0, stream>>>(degi, offs, parts);
  scan2_k<<<1, 64, 0, stream>>>(parts, nblkN);
  scan3_k<<<nblkN, 256, 0, stream>>>(offs, parts);
  place_k<<<(NE + 255) / 256, 256, 0, stream>>>(edst, offs, cnt, eids);
  sort_k<<<nblkN, 256, 0, stream>>>(offs, eids);
  gath_k<<<(NE + 255) / 256, 256, 0, stream>>>(eids, esrc, edst, dinv, eids, norms);
  gum_k<<<(3 * NN + 255) / 256, 256, 0, stream>>>(gum, key[0][0], key[0][1], key[1][0], key[1][1],
                                                  key[2][0], key[2][1]);
  einit_k<<<nblkN, 256, 0, stream>>>(eout);

  const int LB = (NN + 63) / 64;        // lin: 782 blocks, 64 rows each
  const int AB = 8 * (NN / 16);         // agg: 25000 blocks (8 slices x 3125 groups)
  const int DB = (NN + 63) / 64;        // decide: 782 blocks
  for (int l = 0; l < 3; ++l) {
    const float* xin = (l == 0) ? x_in : Q;
    lin_k<<<LB, 256, 0, stream>>>(xin, convw[l], P);
    agg_k<<<AB, 256, 0, stream>>>(P, dinv, offs, eids, norms, convb[l], Q, (l < 2) ? 1 : 0);
    if (l == 0)
      decide_k<0><<<DB, 256, 0, stream>>>(Q, cw1, cb1, cw2, cb2, gum, zout, eout, 0.0f);
    else if (l == 1)
      decide_k<1><<<DB, 256, 0, stream>>>(Q, cw1, cb1, cw2, cb2, gum + (size_t)NN * 2, zout, eout, 1.0f);
    else
      decide_k<2><<<DB, 256, 0, stream>>>(Q, cw1, cb1, cw2, cb2, gum + (size_t)2 * NN * 2, zout, eout, 2.0f);
  }
  cnt_k<<<1, 1024, 0, stream>>>(eout, aout);
}

// Round 7
// 526.857 us; speedup vs baseline: 1.6077x; 1.6077x over previous
//
#include <hip/hip_runtime.h>
#include <stdint.h>

#define NN 50000
#define NE 800000
#define CH 128

typedef double d4 __attribute__((ext_vector_type(4)));

// ---------------- threefry2x32 (exact JAX semantics) ----------------
__host__ __device__ inline void tf2x32(uint32_t k0, uint32_t k1, uint32_t& x0, uint32_t& x1) {
  uint32_t ks2 = k0 ^ k1 ^ 0x1BD11BDAu;
  x0 += k0; x1 += k1;
#define ROTL(v, r) (((v) << (r)) | ((v) >> (32 - (r))))
#define RND(r) { x0 += x1; x1 = ROTL(x1, r); x1 ^= x0; }
  RND(13) RND(15) RND(26) RND(6)
  x0 += k1; x1 += ks2 + 1u;
  RND(17) RND(29) RND(16) RND(24)
  x0 += ks2; x1 += k0 + 2u;
  RND(13) RND(15) RND(26) RND(6)
  x0 += k0; x1 += k1 + 3u;
  RND(17) RND(29) RND(16) RND(24)
  x0 += k1; x1 += ks2 + 4u;
  RND(13) RND(15) RND(26) RND(6)
  x0 += ks2; x1 += k0 + 5u;
#undef RND
#undef ROTL
}

__device__ inline float bits_to_u(uint32_t b) {
  float f = __uint_as_float(0x3F800000u | (b >> 9)) - 1.0f;  // [0,1)
  f = f + 1e-10f;
  return fmaxf(1e-10f, f);
}

// ---------------- graph preprocessing ----------------
__global__ __launch_bounds__(256) void deg_k(const int* __restrict__ dst, int* __restrict__ degi) {
  int i = blockIdx.x * 256 + threadIdx.x;
  if (i < NE) atomicAdd(&degi[dst[i]], 1);
}

__global__ __launch_bounds__(256) void dinv_k(const int* __restrict__ degi, float* __restrict__ dinv) {
  int n = blockIdx.x * 256 + threadIdx.x;
  if (n < NN) {
    float d = (float)(degi[n] + 1);
    dinv[n] = 1.0f / sqrtf(d);
  }
}

__global__ __launch_bounds__(256) void scan1_k(const int* __restrict__ degi, int* __restrict__ offs,
                                               int* __restrict__ part) {
  __shared__ int tmp[256];
  int t = threadIdx.x, b = blockIdx.x, i = b * 256 + t;
  int v = (i < NN) ? degi[i] : 0;
  tmp[t] = v;
  __syncthreads();
  for (int s = 1; s < 256; s <<= 1) {
    int a = (t >= s) ? tmp[t - s] : 0;
    __syncthreads();
    tmp[t] += a;
    __syncthreads();
  }
  int incl = tmp[t];
  if (i < NN) offs[i] = incl - v;
  if (t == 255) part[b] = incl;
}

__global__ void scan2_k(int* part, int nparts) {
  if (threadIdx.x == 0 && blockIdx.x == 0) {
    int run = 0;
    for (int i = 0; i < nparts; ++i) { int v = part[i]; part[i] = run; run += v; }
  }
}

__global__ __launch_bounds__(256) void scan3_k(int* __restrict__ offs, const int* __restrict__ part) {
  int i = blockIdx.x * 256 + threadIdx.x;
  if (i < NN) offs[i] += part[blockIdx.x];
  if (i == 0) offs[NN] = NE;
}

__global__ __launch_bounds__(256) void place_k(const int* __restrict__ dst, const int* __restrict__ offs,
                                               int* __restrict__ cnt, int* __restrict__ eids) {
  int i = blockIdx.x * 256 + threadIdx.x;
  if (i < NE) {
    int d = dst[i];
    int p = offs[d] + atomicAdd(&cnt[d], 1);
    eids[p] = i;
  }
}

// deterministic intra-bucket order = ascending edge id (matches ref segment-sum order)
__global__ __launch_bounds__(256) void sort_k(const int* __restrict__ offs, int* __restrict__ eids) {
  int n = blockIdx.x * 256 + threadIdx.x;
  if (n >= NN) return;
  int s0 = offs[n], s1 = offs[n + 1];
  for (int i = s0 + 1; i < s1; ++i) {
    int v = eids[i];
    int j = i - 1;
    while (j >= s0 && eids[j] > v) { eids[j + 1] = eids[j]; --j; }
    eids[j + 1] = v;
  }
}

// gather src + norm per sorted edge slot; srcs may alias eids (in-place, own-slot RMW)
__global__ __launch_bounds__(256) void gath_k(const int* __restrict__ eids, const int* __restrict__ src,
                                              const int* __restrict__ dst, const float* __restrict__ dinv,
                                              int* __restrict__ srcs, float* __restrict__ norms) {
  int p = blockIdx.x * 256 + threadIdx.x;
  if (p < NE) {
    int e = eids[p];
    int s = src[e];
    float nm = dinv[s] * dinv[dst[e]];
    srcs[p] = s;
    norms[p] = nm;
  }
}

// ---------------- gumbel precompute ----------------
__global__ __launch_bounds__(256) void gum_k(float* __restrict__ gum,
                                             uint32_t k00, uint32_t k01, uint32_t k10, uint32_t k11,
                                             uint32_t k20, uint32_t k21) {
  int i = blockIdx.x * 256 + threadIdx.x;
  if (i >= 3 * NN) return;
  int l = i / NN;
  int n = i - l * NN;
  uint32_t kx, ky;
  if (l == 0) { kx = k00; ky = k01; }
  else if (l == 1) { kx = k10; ky = k11; }
  else { kx = k20; ky = k21; }
  int j0 = 2 * n, j1 = 2 * n + 1;
  uint32_t w0, w1;
  if (j0 < NN) {
    uint32_t a0 = (uint32_t)j0, a1 = (uint32_t)(j0 + NN);
    tf2x32(kx, ky, a0, a1); w0 = a0;
    uint32_t b0 = (uint32_t)j1, b1 = (uint32_t)(j1 + NN);
    tf2x32(kx, ky, b0, b1); w1 = b0;
  } else {
    uint32_t a0 = (uint32_t)(j0 - NN), a1 = (uint32_t)j0;
    tf2x32(kx, ky, a0, a1); w0 = a1;
    uint32_t b0 = (uint32_t)(j1 - NN), b1 = (uint32_t)j1;
    tf2x32(kx, ky, b0, b1); w1 = b1;
  }
  float u0 = bits_to_u(w0), u1 = bits_to_u(w1);
  gum[2 * (size_t)i]     = -logf(-logf(u0));
  gum[2 * (size_t)i + 1] = -logf(-logf(u1));
}

// init exit_layers to 3.0 (doubles as the "still active" state)
__global__ __launch_bounds__(256) void einit_k(float* __restrict__ eout) {
  int i = blockIdx.x * 256 + threadIdx.x;
  if (i < NN) eout[i] = 3.0f;
}

// ---------------- h = x @ W  (f32, 64x128 tile, BK=32, float4 both operands) ----------------
// k-order per output element strictly ascending -> bit-identical h. Node-major output.
__global__ __launch_bounds__(256) void lin_k(const float* __restrict__ x, const float* __restrict__ W,
                                             float* __restrict__ h) {
  __shared__ float Ws[32 * 128];    // [k][c]
  __shared__ float xs[64][36];      // [row][k], padded
  int t = threadIdx.x;
  int row0 = blockIdx.x << 6;
  int tr = t & 15, tc = t >> 4;     // rows tr+16i, col4s tc and 16+tc
  float4 acc[4][2];
#pragma unroll
  for (int i = 0; i < 4; ++i) { acc[i][0] = make_float4(0,0,0,0); acc[i][1] = make_float4(0,0,0,0); }

  for (int kt = 0; kt < 4; ++kt) {
    __syncthreads();
    {
      const float4* W4 = (const float4*)(W + (size_t)(kt * 32) * 128);
      float4* Ws4 = (float4*)Ws;
#pragma unroll
      for (int i = 0; i < 4; ++i) Ws4[t + 256 * i] = W4[t + 256 * i];
    }
    {
#pragma unroll
      for (int i = 0; i < 2; ++i) {
        int f = t + 256 * i;            // 0..511
        int row = f >> 3, c4 = f & 7;
        int gr = row0 + row;
        float4 v = make_float4(0,0,0,0);
        if (gr < NN) v = ((const float4*)x)[(size_t)gr * 32 + kt * 8 + c4];
        *(float4*)&xs[row][4 * c4] = v;
      }
    }
    __syncthreads();
    const float4* Ws4 = (const float4*)Ws;
#pragma unroll
    for (int kk = 0; kk < 32; kk += 4) {
      float4 xv[4];
#pragma unroll
      for (int i = 0; i < 4; ++i) xv[i] = *(const float4*)&xs[tr + 16 * i][kk];
#pragma unroll
      for (int d = 0; d < 4; ++d) {
        float4 w0 = Ws4[(kk + d) * 32 + tc];
        float4 w1 = Ws4[(kk + d) * 32 + 16 + tc];
#pragma unroll
        for (int i = 0; i < 4; ++i) {
          float xd = ((const float*)&xv[i])[d];
          acc[i][0].x += xd * w0.x; acc[i][0].y += xd * w0.y;
          acc[i][0].z += xd * w0.z; acc[i][0].w += xd * w0.w;
          acc[i][1].x += xd * w1.x; acc[i][1].y += xd * w1.y;
          acc[i][1].z += xd * w1.z; acc[i][1].w += xd * w1.w;
        }
      }
    }
  }
#pragma unroll
  for (int i = 0; i < 4; ++i) {
    int gr = row0 + tr + 16 * i;
    if (gr < NN) {
      ((float4*)h)[(size_t)gr * 32 + tc] = acc[i][0];
      ((float4*)h)[(size_t)gr * 32 + 16 + tc] = acc[i][1];
    }
  }
}

// ---------------- sym-normalized aggregate + bias (+ GELU) ----------------
__device__ inline float gelu_exact(float v) {
  return 0.5f * v * (1.0f + erff(v / 1.4142135623730951f));
}

// wave per node, channels (2*lane, 2*lane+1); descriptors lane-parallel + shfl-broadcast,
// 8-wide unroll (8 h-row loads in flight). Per-node add order = ascending edge id,
// self-loop last -> bit-identical to the verified r5 kernel.
__global__ __launch_bounds__(256) void agg_k(const float* __restrict__ h, const float* __restrict__ dinv,
                                             const int* __restrict__ offs, const int* __restrict__ srcs,
                                             const float* __restrict__ norms, const float* __restrict__ bias,
                                             float* __restrict__ xout, int act) {
  int lane = threadIdx.x & 63, w = threadIdx.x >> 6;
  int n = blockIdx.x * 4 + w;
  if (n >= NN) return;
  int s0 = offs[n], s1 = offs[n + 1];
  double a0 = 0.0, a1 = 0.0;
  for (int p0 = s0; p0 < s1; p0 += 64) {
    int m = s1 - p0; if (m > 64) m = 64;
    int sv = 0; float nv = 0.f;
    if (lane < m) {
      sv = __builtin_nontemporal_load(&srcs[p0 + lane]);
      nv = __builtin_nontemporal_load(&norms[p0 + lane]);
    }
    int i = 0;
    for (; i + 8 <= m; i += 8) {
      int   sA = __shfl(sv, i),     sB = __shfl(sv, i + 1), sC = __shfl(sv, i + 2), sD = __shfl(sv, i + 3);
      int   sE = __shfl(sv, i + 4), sF = __shfl(sv, i + 5), sG = __shfl(sv, i + 6), sH = __shfl(sv, i + 7);
      float nA = __shfl(nv, i),     nB = __shfl(nv, i + 1), nC = __shfl(nv, i + 2), nD = __shfl(nv, i + 3);
      float nE = __shfl(nv, i + 4), nF = __shfl(nv, i + 5), nG = __shfl(nv, i + 6), nH = __shfl(nv, i + 7);
      float2 hA = *(const float2*)&h[(size_t)sA * CH + 2 * lane];
      float2 hB = *(const float2*)&h[(size_t)sB * CH + 2 * lane];
      float2 hC = *(const float2*)&h[(size_t)sC * CH + 2 * lane];
      float2 hD = *(const float2*)&h[(size_t)sD * CH + 2 * lane];
      float2 hE = *(const float2*)&h[(size_t)sE * CH + 2 * lane];
      float2 hF = *(const float2*)&h[(size_t)sF * CH + 2 * lane];
      float2 hG = *(const float2*)&h[(size_t)sG * CH + 2 * lane];
      float2 hH = *(const float2*)&h[(size_t)sH * CH + 2 * lane];
      a0 += (double)(hA.x * nA); a1 += (double)(hA.y * nA);
      a0 += (double)(hB.x * nB); a1 += (double)(hB.y * nB);
      a0 += (double)(hC.x * nC); a1 += (double)(hC.y * nC);
      a0 += (double)(hD.x * nD); a1 += (double)(hD.y * nD);
      a0 += (double)(hE.x * nE); a1 += (double)(hE.y * nE);
      a0 += (double)(hF.x * nF); a1 += (double)(hF.y * nF);
      a0 += (double)(hG.x * nG); a1 += (double)(hG.y * nG);
      a0 += (double)(hH.x * nH); a1 += (double)(hH.y * nH);
    }
    for (; i + 4 <= m; i += 4) {
      int   sA = __shfl(sv, i),     sB = __shfl(sv, i + 1), sC = __shfl(sv, i + 2), sD = __shfl(sv, i + 3);
      float nA = __shfl(nv, i),     nB = __shfl(nv, i + 1), nC = __shfl(nv, i + 2), nD = __shfl(nv, i + 3);
      float2 hA = *(const float2*)&h[(size_t)sA * CH + 2 * lane];
      float2 hB = *(const float2*)&h[(size_t)sB * CH + 2 * lane];
      float2 hC = *(const float2*)&h[(size_t)sC * CH + 2 * lane];
      float2 hD = *(const float2*)&h[(size_t)sD * CH + 2 * lane];
      a0 += (double)(hA.x * nA); a1 += (double)(hA.y * nA);
      a0 += (double)(hB.x * nB); a1 += (double)(hB.y * nB);
      a0 += (double)(hC.x * nC); a1 += (double)(hC.y * nC);
      a0 += (double)(hD.x * nD); a1 += (double)(hD.y * nD);
    }
    for (; i < m; ++i) {
      int   s = __shfl(sv, i);
      float nm = __shfl(nv, i);
      float2 hv = *(const float2*)&h[(size_t)s * CH + 2 * lane];
      a0 += (double)(hv.x * nm); a1 += (double)(hv.y * nm);
    }
  }
  float dv = dinv[n];
  float selfn = dv * dv;  // self-loop appended last, like ref
  float2 hn = *(const float2*)&h[(size_t)n * CH + 2 * lane];
  a0 += (double)(hn.x * selfn); a1 += (double)(hn.y * selfn);
  float r0 = (float)a0 + bias[2 * lane];
  float r1 = (float)a1 + bias[2 * lane + 1];
  if (act) { r0 = gelu_exact(r0); r1 = gelu_exact(r1); }
  float2 o; o.x = r0; o.y = r1;
  *(float2*)&xout[(size_t)n * CH + 2 * lane] = o;
}

// ---------------- confidence MLP + gumbel decision via f64 MFMA ----------------
// W1 read from GLOBAL (L1-resident, 32KB) -> LDS is xs-only (~34KB) -> 4 blocks/CU.
// eout (init 3.0) is the state; no atomics. Numerics identical to the verified kernel.
template <int MODE>
__global__ __launch_bounds__(256) void decide_k(const float* __restrict__ x, const float* __restrict__ W1,
                                                const float* __restrict__ b1, const float* __restrict__ W2,
                                                const float* __restrict__ b2, const float* __restrict__ gum,
                                                float* __restrict__ zout, float* __restrict__ eout,
                                                float layerf) {
  __shared__ float b1s[64];
  __shared__ float w2s[128];
  __shared__ float b2s[2];
  __shared__ float xs[4][16][132];
  int t = threadIdx.x;
  if (t < 64) b1s[t] = b1[t];
  if (t < 128) w2s[t] = W2[t];
  if (t < 2) b2s[t] = b2[t];

  int lane = t & 63, w = t >> 6;
  int n0 = blockIdx.x * 64 + w * 16;
#pragma unroll
  for (int i = 0; i < 8; ++i) {
    int f = lane + 64 * i;
    int row = f >> 5, c4 = f & 31;
    int gr = n0 + row;
    float4 v = make_float4(0.f, 0.f, 0.f, 0.f);
    if (gr < NN) v = ((const float4*)x)[(size_t)gr * 32 + c4];
    *(float4*)&xs[w][row][4 * c4] = v;
  }

  int g = lane >> 4, r = lane & 15;
  bool writer = (r < 4);
  int mynode = n0 + 4 * g + r;
  float ev = 3.0f;
  float gg0 = 0.f, gg1 = 0.f;
  if (writer && mynode < NN) {
    if (MODE > 0) ev = eout[mynode];
    gg0 = gum[2 * (size_t)mynode];       // hoisted: hide latency under MFMA loop
    gg1 = gum[2 * (size_t)mynode + 1];
  }
  bool m_act = writer && (mynode < NN) && (MODE == 0 || ev == 3.0f);
  unsigned long long actmask = __ballot(m_act);
  __syncthreads();
  if (MODE > 0 && actmask == 0ULL) return;

  d4 acc0 = {0., 0., 0., 0.}, acc1 = {0., 0., 0., 0.};
  d4 acc2 = {0., 0., 0., 0.}, acc3 = {0., 0., 0., 0.};
#pragma unroll 4
  for (int ks = 0; ks < 32; ++ks) {
    int k = 4 * ks + g;
    double av = (double)xs[w][r][k];
    const float* Wk = W1 + (size_t)k * 64;
    double b0 = (double)Wk[r];
    double b1v = (double)Wk[16 + r];
    double b2v = (double)Wk[32 + r];
    double b3v = (double)Wk[48 + r];
    acc0 = __builtin_amdgcn_mfma_f64_16x16x4f64(av, b0, acc0, 0, 0, 0);
    acc1 = __builtin_amdgcn_mfma_f64_16x16x4f64(av, b1v, acc1, 0, 0, 0);
    acc2 = __builtin_amdgcn_mfma_f64_16x16x4f64(av, b2v, acc2, 0, 0, 0);
    acc3 = __builtin_amdgcn_mfma_f64_16x16x4f64(av, b3v, acc3, 0, 0, 0);
  }

  double p0[4], p1[4];
#pragma unroll
  for (int i = 0; i < 4; ++i) {
    float h0 = fmaxf((float)acc0[i] + b1s[r], 0.f);
    float h1 = fmaxf((float)acc1[i] + b1s[16 + r], 0.f);
    float h2 = fmaxf((float)acc2[i] + b1s[32 + r], 0.f);
    float h3 = fmaxf((float)acc3[i] + b1s[48 + r], 0.f);
    double q0 = (double)h0 * (double)w2s[2 * r] + (double)h1 * (double)w2s[2 * (16 + r)] +
                (double)h2 * (double)w2s[2 * (32 + r)] + (double)h3 * (double)w2s[2 * (48 + r)];
    double q1 = (double)h0 * (double)w2s[2 * r + 1] + (double)h1 * (double)w2s[2 * (16 + r) + 1] +
                (double)h2 * (double)w2s[2 * (32 + r) + 1] + (double)h3 * (double)w2s[2 * (48 + r) + 1];
#pragma unroll
    for (int off = 1; off <= 8; off <<= 1) {
      q0 += __shfl_xor(q0, off);
      q1 += __shfl_xor(q1, off);
    }
    p0[i] = q0; p1[i] = q1;
  }

  double q0sel = p0[0], q1sel = p1[0];
  if (r == 1) { q0sel = p0[1]; q1sel = p1[1]; }
  if (r == 2) { q0sel = p0[2]; q1sel = p1[2]; }
  if (r == 3) { q0sel = p0[3]; q1sel = p1[3]; }
  bool myex = false;
  if (writer && mynode < NN) {
    float l0 = (float)q0sel + b2s[0];
    float l1 = (float)q1sel + b2s[1];
    myex = (l1 + gg1) > (l0 + gg0);
  }
  unsigned long long exmask = __ballot(myex);

  if (m_act && myex) eout[mynode] = layerf;

#pragma unroll
  for (int i = 0; i < 16; ++i) {
    int bitpos = 16 * (i >> 2) + (i & 3);
    bool a = (actmask >> bitpos) & 1ULL;
    bool ee = (exmask >> bitpos) & 1ULL;
    if (a && (MODE == 2 || ee)) {
      int node = n0 + i;
      float2 v;
      v.x = xs[w][i][2 * lane];
      v.y = xs[w][i][2 * lane + 1];
      *(float2*)&zout[(size_t)node * CH + 2 * lane] = v;
    }
  }
}

// single-block count of active[] from eout; no atomics
__global__ __launch_bounds__(1024) void cnt_k(const float* __restrict__ eout, float* __restrict__ aout) {
  __shared__ int s1[16], s2[16];
  int t = threadIdx.x;
  int c1 = 0, c2 = 0;
  for (int i = t; i < NN; i += 1024) {
    float v = eout[i];
    c1 += (v < 0.5f);
    c2 += (v < 1.5f);
  }
#pragma unroll
  for (int off = 32; off >= 1; off >>= 1) { c1 += __shfl_xor(c1, off); c2 += __shfl_xor(c2, off); }
  if ((t & 63) == 0) { s1[t >> 6] = c1; s2[t >> 6] = c2; }
  __syncthreads();
  if (t == 0) {
    int a1 = 0, a2 = 0;
#pragma unroll
    for (int i = 0; i < 16; ++i) { a1 += s1[i]; a2 += s2[i]; }
    aout[0] = 50000.0f;
    aout[1] = (float)(NN - a1);
    aout[2] = (float)(NN - a2);
  }
}

// ---------------- host ----------------
extern "C" void kernel_launch(void* const* d_in, const int* in_sizes, int n_in,
                              void* d_out, int out_size, void* d_ws, size_t ws_size,
                              hipStream_t stream) {
  const float* x_in = (const float*)d_in[0];
  const int* eidx = (const int*)d_in[1];
  const int* esrc = eidx;
  const int* edst = eidx + NE;
  const float* convw[3] = {(const float*)d_in[2], (const float*)d_in[4], (const float*)d_in[6]};
  const float* convb[3] = {(const float*)d_in[3], (const float*)d_in[5], (const float*)d_in[7]};
  const float* cw1 = (const float*)d_in[8];
  const float* cb1 = (const float*)d_in[9];
  const float* cw2 = (const float*)d_in[10];
  const float* cb2 = (const float*)d_in[11];
  // d_in[12] = temp_w: unused (temperature > 0 cancels in the argmax)

  float* out = (float*)d_out;
  float* zout = out;
  float* eout = out + (size_t)NN * CH;
  float* aout = eout + NN;

  char* w = (char*)d_ws;
  float* P = (float*)w;   w += (size_t)NN * CH * 4;
  float* Q = (float*)w;   w += (size_t)NN * CH * 4;
  int* eids = (int*)w;    w += (size_t)NE * 4;        // becomes srcs in-place after gath_k
  float* norms = (float*)w; w += (size_t)NE * 4;
  float* gum = (float*)w; w += (size_t)3 * NN * 2 * 4;
  int* offs = (int*)w;    w += (size_t)(NN + 1) * 4;
  float* dinv = (float*)w; w += (size_t)NN * 4;
  char* zr0 = w;
  int* degi = (int*)w;    w += (size_t)NN * 4;
  int* cnt = (int*)w;     w += (size_t)NN * 4;
  int* parts = (int*)w;   w += 1024;

  hipMemsetAsync(zr0, 0, (size_t)(2 * NN) * 4, stream);

  uint32_t key[3][2];
  for (int l = 0; l < 3; ++l) {
    uint32_t a = 0u, b = (uint32_t)l;
    tf2x32(0u, 42u, a, b);
    key[l][0] = a; key[l][1] = b;
  }

  const int nblkN = (NN + 255) / 256;
  deg_k<<<(NE + 255) / 256, 256, 0, stream>>>(edst, degi);
  dinv_k<<<nblkN, 256, 0, stream>>>(degi, dinv);
  scan1_k<<<nblkN, 256, 0, stream>>>(degi, offs, parts);
  scan2_k<<<1, 64, 0, stream>>>(parts, nblkN);
  scan3_k<<<nblkN, 256, 0, stream>>>(offs, parts);
  place_k<<<(NE + 255) / 256, 256, 0, stream>>>(edst, offs, cnt, eids);
  sort_k<<<nblkN, 256, 0, stream>>>(offs, eids);
  gath_k<<<(NE + 255) / 256, 256, 0, stream>>>(eids, esrc, edst, dinv, eids, norms);
  gum_k<<<(3 * NN + 255) / 256, 256, 0, stream>>>(gum, key[0][0], key[0][1], key[1][0], key[1][1],
                                                  key[2][0], key[2][1]);
  einit_k<<<nblkN, 256, 0, stream>>>(eout);

  const int LB = (NN + 63) / 64;   // lin: 782 blocks
  const int AB = (NN + 3) / 4;     // agg: 12500 blocks
  const int DB = (NN + 63) / 64;   // decide: 782 blocks
  for (int l = 0; l < 3; ++l) {
    const float* xin = (l == 0) ? x_in : Q;
    lin_k<<<LB, 256, 0, stream>>>(xin, convw[l], P);
    agg_k<<<AB, 256, 0, stream>>>(P, dinv, offs, eids, norms, convb[l], Q, (l < 2) ? 1 : 0);
    if (l == 0)
      decide_k<0><<<DB, 256, 0, stream>>>(Q, cw1, cb1, cw2, cb2, gum, zout, eout, 0.0f);
    else if (l == 1)
      decide_k<1><<<DB, 256, 0, stream>>>(Q, cw1, cb1, cw2, cb2, gum + (size_t)NN * 2, zout, eout, 1.0f);
    else
      decide_k<2><<<DB, 256, 0, stream>>>(Q, cw1, cb1, cw2, cb2, gum + (size_t)2 * NN * 2, zout, eout, 2.0f);
  }
  cnt_k<<<1, 1024, 0, stream>>>(eout, aout);
}